// Round 10
// baseline (111.327 us; speedup 1.0000x reference)
//
#include <hip/hip_runtime.h>
#include <hip/hip_bf16.h>

// PeptideSelfAttention: B=16 N=256 CS=256 CH=64 H=8 K=32 CT=1024 NB=65
// R10: 6 launches. FFN1 fuses LN1 (in-block row LN -> swizzled LDS A, side-
// writes s1 once). FFN2 fuses bias+resid(s1)+LN2 with direct-global frags
// (no LDS staging, no K-loop barriers), BM=16 x BN=256 full-row blocks.

#define N_TOK 256
#define CH 64
#define NH 8
#define NB 65

typedef __attribute__((ext_vector_type(8))) __bf16 bf16x8;
typedef __attribute__((ext_vector_type(4))) float f32x4;
typedef __attribute__((ext_vector_type(16))) float f32x16;

__device__ inline unsigned short f2bf(float f) {
  unsigned int u = __float_as_uint(f);
  u = (u + 0x7FFFu + ((u >> 16) & 1u)) >> 16;
  return (unsigned short)u;
}
__device__ inline float bf2f(unsigned short u) {
  return __uint_as_float(((unsigned int)u) << 16);
}

// ------------------------------------------------------------ fused prep
__global__ __launch_bounds__(256) void prep_all(
    const float* __restrict__ s, const float* __restrict__ Wq,
    const float* __restrict__ Wk, const float* __restrict__ Wv,
    const float* __restrict__ Wo, const float* __restrict__ W1,
    const float* __restrict__ W2,
    unsigned short* __restrict__ s_bf, unsigned short* __restrict__ wqkv_t,
    unsigned short* __restrict__ wo_t, unsigned short* __restrict__ w1_t,
    unsigned short* __restrict__ w2_t)
{
  const int bid = blockIdx.x, tid = threadIdx.x;
  if (bid < 1024) {
    int idx = (bid * 256 + tid) * 4;
    float4 v = *(const float4*)(s + idx);
    ushort4 o;
    o.x = f2bf(v.x); o.y = f2bf(v.y); o.z = f2bf(v.z); o.w = f2bf(v.w);
    *(ushort4*)(s_bf + idx) = o;
    return;
  }
  int j = bid - 1024;
  const float* in; unsigned short* out;
  int R, C, ldout, r0, c0, qkvperm = 0;
  if (j < 96) {
    int mat = j / 32, jj = j % 32;
    r0 = (jj / 8) * 64; c0 = (jj % 8) * 64;
    in = (mat == 0) ? Wq : (mat == 1) ? Wk : Wv;
    R = 256; C = 512; out = wqkv_t + mat * 131072; ldout = 256; qkvperm = 1;
  } else if (j < 164) {
    int jj = j - 96;
    r0 = (jj / 4) * 64; c0 = (jj % 4) * 64;
    in = Wo; R = 1032; C = 256; out = wo_t; ldout = 1056;
  } else if (j < 228) {
    int jj = j - 164;
    r0 = (jj / 16) * 64; c0 = (jj % 16) * 64;
    in = W1; R = 256; C = 1024; out = w1_t; ldout = 256;
  } else {
    int jj = j - 228;
    r0 = (jj / 4) * 64; c0 = (jj % 4) * 64;
    in = W2; R = 1024; C = 256; out = w2_t; ldout = 1024;
  }
  __shared__ unsigned short lt[64][72];
#pragma unroll
  for (int it = 0; it < 4; ++it) {
    int kk = it * 16 + (tid >> 4);
    int cc = (tid & 15) * 4;
    float4 v = {0.f, 0.f, 0.f, 0.f};
    if (r0 + kk < R) v = *(const float4*)(in + (size_t)(r0 + kk) * C + c0 + cc);
    lt[cc + 0][kk] = f2bf(v.x); lt[cc + 1][kk] = f2bf(v.y);
    lt[cc + 2][kk] = f2bf(v.z); lt[cc + 3][kk] = f2bf(v.w);
  }
  __syncthreads();
  {
    int or_ = tid >> 2, chunk = tid & 3;
    int ocol0 = r0 + chunk * 16;
    int orow = c0 + or_;
    if (qkvperm) orow = (orow & 7) * 64 + (orow >> 3);
    if (ocol0 < ldout) {
      uint4 w0 = *(uint4*)&lt[or_][chunk * 16];
      uint4 w1 = *(uint4*)&lt[or_][chunk * 16 + 8];
      *(uint4*)(out + (size_t)orow * ldout + ocol0) = w0;
      *(uint4*)(out + (size_t)orow * ldout + ocol0 + 8) = w1;
    }
  }
}

// --------------------------------------------- 128x128 MFMA GEMM (QKV)
__global__ __launch_bounds__(256) void gemm_mfma(
    const unsigned short* __restrict__ A, const unsigned short* __restrict__ Bt,
    int M, int N, int K,
    unsigned short* __restrict__ qk, unsigned short* __restrict__ vt)
{
  __shared__ __align__(16) char Asb[4][8192];
  __shared__ __align__(16) char Bsb[4][8192];
  const int tid = threadIdx.x;
  const int w = tid >> 6, lane = tid & 63;
  const int wm = w >> 1, wn = w & 1;
  const int nbx = gridDim.x;
  int flat = blockIdx.y * nbx + blockIdx.x;
  int cpx = (nbx * gridDim.y) >> 3;
  int swz = (flat & 7) * cpx + (flat >> 3);
  const int m0 = (swz / nbx) * 128, n0 = (swz % nbx) * 128;
  const int fr = lane & 15, kq = lane >> 4;

  const unsigned short *pa[2], *pb[2];
  int ldsoff[2];
#pragma unroll
  for (int s2 = 0; s2 < 2; ++s2) {
    int inst = w * 2 + s2;
    int row = inst * 16 + (lane >> 2);
    int ch = (lane & 3) ^ ((row >> 1) & 3);
    pa[s2] = A + (size_t)(m0 + row) * K + ch * 8;
    pb[s2] = Bt + (size_t)(n0 + row) * K + ch * 8;
    ldsoff[s2] = inst * 1024;
  }
  auto stage = [&](int buf, int koff) {
#pragma unroll
    for (int s2 = 0; s2 < 2; ++s2) {
      __builtin_amdgcn_global_load_lds(
          (const __attribute__((address_space(1))) void*)(pa[s2] + koff),
          (__attribute__((address_space(3))) void*)(Asb[buf] + ldsoff[s2]), 16, 0, 0);
      __builtin_amdgcn_global_load_lds(
          (const __attribute__((address_space(1))) void*)(pb[s2] + koff),
          (__attribute__((address_space(3))) void*)(Bsb[buf] + ldsoff[s2]), 16, 0, 0);
    }
  };

  f32x4 acc[4][4];
#pragma unroll
  for (int m = 0; m < 4; ++m)
#pragma unroll
    for (int n = 0; n < 4; ++n)
#pragma unroll
      for (int e = 0; e < 4; ++e) acc[m][n][e] = 0.f;

  const int nsteps = K >> 5;
  stage(0, 0);
  if (nsteps > 1) stage(1, 32);
  if (nsteps > 2) stage(2, 64);

  for (int t = 0; t < nsteps; ++t) {
    if (t + 3 < nsteps) stage((t + 3) & 3, (t + 3) * 32);
    int ahead = nsteps - 1 - t; if (ahead > 3) ahead = 3;
    switch (ahead) {
      case 3: asm volatile("s_waitcnt vmcnt(12)" ::: "memory"); break;
      case 2: asm volatile("s_waitcnt vmcnt(8)" ::: "memory"); break;
      case 1: asm volatile("s_waitcnt vmcnt(4)" ::: "memory"); break;
      default: asm volatile("s_waitcnt vmcnt(0)" ::: "memory"); break;
    }
    __builtin_amdgcn_s_barrier();

    const char* Ac = Asb[t & 3];
    const char* Bc = Bsb[t & 3];
    bf16x8 af[4], bfr[4];
#pragma unroll
    for (int m = 0; m < 4; ++m) {
      int r = wm * 64 + m * 16 + fr;
      af[m] = *(const bf16x8*)(Ac + r * 64 + ((kq ^ ((r >> 1) & 3)) << 4));
    }
#pragma unroll
    for (int n = 0; n < 4; ++n) {
      int r = wn * 64 + n * 16 + fr;
      bfr[n] = *(const bf16x8*)(Bc + r * 64 + ((kq ^ ((r >> 1) & 3)) << 4));
    }
#pragma unroll
    for (int m = 0; m < 4; ++m)
#pragma unroll
      for (int n = 0; n < 4; ++n)
        acc[m][n] = __builtin_amdgcn_mfma_f32_16x16x32_bf16(af[m], bfr[n], acc[m][n], 0, 0, 0);

    __builtin_amdgcn_s_barrier();
  }

  const int colbase = n0 + wn * 64;
  const int rowbase = m0 + wm * 64 + kq * 4;
#pragma unroll
  for (int mi = 0; mi < 4; ++mi)
#pragma unroll
    for (int ni = 0; ni < 4; ++ni) {
      int col = colbase + ni * 16 + fr;
      int rb = rowbase + mi * 16;
      if (col < 1024) {
#pragma unroll
        for (int r = 0; r < 4; ++r)
          qk[(size_t)(rb + r) * 1024 + col] = f2bf(acc[mi][ni][r]);
      } else {
        int r2 = col & 511;
        int h = r2 >> 6, c = r2 & 63;
        int b = rb >> 8, i = rb & 255;
        union { unsigned short u4[4]; uint2 v; } pk;
#pragma unroll
        for (int r = 0; r < 4; ++r) pk.u4[r] = f2bf(acc[mi][ni][r]);
        *(uint2*)(vt + (((size_t)(b * NH + h)) * CH + c) * N_TOK + i) = pk.v;
      }
    }
}

// --------------------------------------------- 64x64 MFMA GEMM (Wo)
__global__ __launch_bounds__(256) void gemm_mfma64(
    const unsigned short* __restrict__ A, const unsigned short* __restrict__ Bt,
    int M, int N, int K, const float* __restrict__ bias,
    float* __restrict__ Cf, int ldc, const float* __restrict__ resid)
{
  __shared__ __align__(16) char Asb[4][4096];
  __shared__ __align__(16) char Bsb[4][4096];
  const int tid = threadIdx.x;
  const int w = tid >> 6, lane = tid & 63;
  const int wm = w >> 1, wn = w & 1;
  const int m0 = blockIdx.y * 64, n0 = blockIdx.x * 64;
  const int fr = lane & 15, kq = lane >> 4;

  const int srow = w * 16 + (lane >> 2);
  const int sch = (lane & 3) ^ ((srow >> 1) & 3);
  const unsigned short* pa = A + (size_t)(m0 + srow) * K + sch * 8;
  const unsigned short* pb = Bt + (size_t)(n0 + srow) * K + sch * 8;

  auto stage = [&](int buf, int koff) {
    __builtin_amdgcn_global_load_lds(
        (const __attribute__((address_space(1))) void*)(pa + koff),
        (__attribute__((address_space(3))) void*)(Asb[buf] + w * 1024), 16, 0, 0);
    __builtin_amdgcn_global_load_lds(
        (const __attribute__((address_space(1))) void*)(pb + koff),
        (__attribute__((address_space(3))) void*)(Bsb[buf] + w * 1024), 16, 0, 0);
  };

  f32x4 acc[2][2];
#pragma unroll
  for (int m = 0; m < 2; ++m)
#pragma unroll
    for (int n = 0; n < 2; ++n)
#pragma unroll
      for (int e = 0; e < 4; ++e) acc[m][n][e] = 0.f;

  const int nsteps = K >> 5;
  stage(0, 0);
  if (nsteps > 1) stage(1, 32);
  if (nsteps > 2) stage(2, 64);

  for (int t = 0; t < nsteps; ++t) {
    if (t + 3 < nsteps) stage((t + 3) & 3, (t + 3) * 32);
    int ahead = nsteps - 1 - t; if (ahead > 3) ahead = 3;
    switch (ahead) {
      case 3: asm volatile("s_waitcnt vmcnt(6)" ::: "memory"); break;
      case 2: asm volatile("s_waitcnt vmcnt(4)" ::: "memory"); break;
      case 1: asm volatile("s_waitcnt vmcnt(2)" ::: "memory"); break;
      default: asm volatile("s_waitcnt vmcnt(0)" ::: "memory"); break;
    }
    __builtin_amdgcn_s_barrier();

    const char* Ac = Asb[t & 3];
    const char* Bc = Bsb[t & 3];
    bf16x8 af[2], bfr[2];
#pragma unroll
    for (int m = 0; m < 2; ++m) {
      int r = wm * 32 + m * 16 + fr;
      af[m] = *(const bf16x8*)(Ac + r * 64 + ((kq ^ ((r >> 1) & 3)) << 4));
    }
#pragma unroll
    for (int n = 0; n < 2; ++n) {
      int r = wn * 32 + n * 16 + fr;
      bfr[n] = *(const bf16x8*)(Bc + r * 64 + ((kq ^ ((r >> 1) & 3)) << 4));
    }
#pragma unroll
    for (int m = 0; m < 2; ++m)
#pragma unroll
      for (int n = 0; n < 2; ++n)
        acc[m][n] = __builtin_amdgcn_mfma_f32_16x16x32_bf16(af[m], bfr[n], acc[m][n], 0, 0, 0);

    __builtin_amdgcn_s_barrier();
  }

  const int colbase = n0 + wn * 32;
  const int rowbase = m0 + wm * 32 + kq * 4;
#pragma unroll
  for (int mi = 0; mi < 2; ++mi)
#pragma unroll
    for (int ni = 0; ni < 2; ++ni) {
      int col = colbase + ni * 16 + fr;
      int rb = rowbase + mi * 16;
      float bv = bias[col];
#pragma unroll
      for (int r = 0; r < 4; ++r) {
        float rv = resid[(size_t)(rb + r) * ldc + col];
        Cf[(size_t)(rb + r) * ldc + col] = acc[mi][ni][r] + bv + rv;
      }
    }
}

// ----------------------------- FFN1 + fused LN1 (A built in-block from s_upd)
// BM=64, BN=64, K=256; grid (16,64). Phase A: per-row LN (full 256-col rows),
// bf16 A into swizzled LDS; blocks bx==0 also write s1 f32. Then B-staged K-loop.
__global__ __launch_bounds__(256) void gemm_ffn1(
    const float* __restrict__ s_upd, const unsigned short* __restrict__ w1t,
    const float* __restrict__ g1, const float* __restrict__ b1,
    const float* __restrict__ bf1,
    unsigned short* __restrict__ hbuf, float* __restrict__ s1out)
{
  __shared__ __align__(16) char A_lds[64 * 512];   // [row][256 bf16] 16-chunk XOR
  __shared__ __align__(16) char Bsb[4][4096];
  const int tid = threadIdx.x;
  const int w = tid >> 6, lane = tid & 63;
  const int wm = w >> 1, wn = w & 1;
  const int m0 = blockIdx.y * 64, n0 = blockIdx.x * 64;
  const int fr = lane & 15, kq = lane >> 4;

  // ---- phase A: LN1 of s_upd rows [m0, m0+64)
  {
    float4 gv = *(const float4*)(g1 + lane * 4);
    float4 bv = *(const float4*)(b1 + lane * 4);
    for (int rr = 0; rr < 16; ++rr) {
      int row_l = w * 16 + rr;
      int grow = m0 + row_l;
      float4 v = *(const float4*)(s_upd + (size_t)grow * 256 + lane * 4);
      float sum = v.x + v.y + v.z + v.w;
      float sq = v.x * v.x + v.y * v.y + v.z * v.z + v.w * v.w;
#pragma unroll
      for (int off = 32; off; off >>= 1) {
        sum += __shfl_xor(sum, off);
        sq += __shfl_xor(sq, off);
      }
      float mu = sum * (1.f / 256.f);
      float rs = rsqrtf(sq * (1.f / 256.f) - mu * mu + 1e-5f);
      float4 y;
      y.x = (v.x - mu) * rs * gv.x + bv.x;
      y.y = (v.y - mu) * rs * gv.y + bv.y;
      y.z = (v.z - mu) * rs * gv.z + bv.z;
      y.w = (v.w - mu) * rs * gv.w + bv.w;
      if (blockIdx.x == 0)
        *(float4*)(s1out + (size_t)grow * 256 + lane * 4) = y;
      union { unsigned short u4[4]; uint2 u; } pk;
      pk.u4[0] = f2bf(y.x); pk.u4[1] = f2bf(y.y);
      pk.u4[2] = f2bf(y.z); pk.u4[3] = f2bf(y.w);
      // chunk = lane>>1 (16B), sub = (lane&1)*8; XOR low 4 bits with row
      *(uint2*)(A_lds + row_l * 512 + (((lane >> 1) ^ (row_l & 15)) << 4) + (lane & 1) * 8) = pk.u;
    }
  }

  // ---- B staging setup
  const int srow = tid >> 2;
  const int sch = (tid & 3) ^ ((srow >> 1) & 3);
  const unsigned short* pb = w1t + (size_t)(n0 + srow) * 256 + sch * 8;
  auto stageB = [&](int buf, int koff) {
    __builtin_amdgcn_global_load_lds(
        (const __attribute__((address_space(1))) void*)(pb + koff),
        (__attribute__((address_space(3))) void*)(Bsb[buf] + w * 1024), 16, 0, 0);
  };

  f32x4 acc[2][2];
#pragma unroll
  for (int m = 0; m < 2; ++m)
#pragma unroll
    for (int n = 0; n < 2; ++n)
#pragma unroll
      for (int e = 0; e < 4; ++e) acc[m][n][e] = 0.f;

  stageB(0, 0);
  stageB(1, 32);
  stageB(2, 64);
  __syncthreads();   // A_lds writes visible; buf0 not yet guaranteed (vmcnt below)

  const int nsteps = 8;
  for (int t = 0; t < nsteps; ++t) {
    if (t + 3 < nsteps) stageB((t + 3) & 3, (t + 3) * 32);
    int ahead = nsteps - 1 - t; if (ahead > 3) ahead = 3;
    switch (ahead) {
      case 3: asm volatile("s_waitcnt vmcnt(3)" ::: "memory"); break;
      case 2: asm volatile("s_waitcnt vmcnt(2)" ::: "memory"); break;
      case 1: asm volatile("s_waitcnt vmcnt(1)" ::: "memory"); break;
      default: asm volatile("s_waitcnt vmcnt(0)" ::: "memory"); break;
    }
    __builtin_amdgcn_s_barrier();

    const char* Bc = Bsb[t & 3];
    bf16x8 af[2], bfr[2];
#pragma unroll
    for (int m = 0; m < 2; ++m) {
      int r = wm * 32 + m * 16 + fr;
      af[m] = *(const bf16x8*)(A_lds + r * 512 + ((((t << 2) + kq) ^ (r & 15)) << 4));
    }
#pragma unroll
    for (int n = 0; n < 2; ++n) {
      int r = wn * 32 + n * 16 + fr;
      bfr[n] = *(const bf16x8*)(Bc + r * 64 + ((kq ^ ((r >> 1) & 3)) << 4));
    }
#pragma unroll
    for (int m = 0; m < 2; ++m)
#pragma unroll
      for (int n = 0; n < 2; ++n)
        acc[m][n] = __builtin_amdgcn_mfma_f32_16x16x32_bf16(af[m], bfr[n], acc[m][n], 0, 0, 0);

    __builtin_amdgcn_s_barrier();
  }

  const int colbase = n0 + wn * 32;
  const int rowbase = m0 + wm * 32 + kq * 4;
#pragma unroll
  for (int mi = 0; mi < 2; ++mi)
#pragma unroll
    for (int ni = 0; ni < 2; ++ni) {
      int col = colbase + ni * 16 + fr;
      int rb = rowbase + mi * 16;
      float bv = bf1[col];
#pragma unroll
      for (int r = 0; r < 4; ++r)
        hbuf[(size_t)(rb + r) * 1024 + col] = f2bf(fmaxf(acc[mi][ni][r] + bv, 0.f));
    }
}

// ------------------- FFN2 + bias + resid(s1) + LN2 (direct-global fragments)
// BM=16, BN=256 (full row); grid 256 blocks, 512 thr (8 waves, 32 cols each).
__global__ __launch_bounds__(512) void gemm_ffn2(
    const unsigned short* __restrict__ hbuf, const unsigned short* __restrict__ w2t,
    const float* __restrict__ bf2, const float* __restrict__ s1,
    const float* __restrict__ g2, const float* __restrict__ b2,
    float* __restrict__ outf)
{
  __shared__ float s1_lds[16][260];
  __shared__ float part_s[8][16], part_q[8][16];
  __shared__ float ln_mu[16], ln_rs[16];

  const int tid = threadIdx.x;
  const int w = tid >> 6, lane = tid & 63;
  const int m0 = blockIdx.x * 16;
  const int fr = lane & 15, kq = lane >> 4;

  // load s1 residual rows
  {
    int row = tid >> 5, c0 = (tid & 31) * 8;
    float4 a = *(const float4*)(s1 + (size_t)(m0 + row) * 256 + c0);
    float4 b = *(const float4*)(s1 + (size_t)(m0 + row) * 256 + c0 + 4);
    *(float4*)&s1_lds[row][c0] = a;
    *(float4*)&s1_lds[row][c0 + 4] = b;
  }
  __syncthreads();

  f32x4 acc[2];
#pragma unroll
  for (int n = 0; n < 2; ++n)
#pragma unroll
    for (int e = 0; e < 4; ++e) acc[n][e] = 0.f;

  const unsigned short* arow = hbuf + (size_t)(m0 + fr) * 1024 + kq * 8;
  const unsigned short* brow0 = w2t + (size_t)(w * 32 + 0 * 16 + fr) * 1024 + kq * 8;
  const unsigned short* brow1 = w2t + (size_t)(w * 32 + 1 * 16 + fr) * 1024 + kq * 8;

#pragma unroll 4
  for (int t = 0; t < 32; ++t) {
    bf16x8 af = *(const bf16x8*)(arow + t * 32);
    bf16x8 b0 = *(const bf16x8*)(brow0 + t * 32);
    bf16x8 b1v = *(const bf16x8*)(brow1 + t * 32);
    acc[0] = __builtin_amdgcn_mfma_f32_16x16x32_bf16(af, b0, acc[0], 0, 0, 0);
    acc[1] = __builtin_amdgcn_mfma_f32_16x16x32_bf16(af, b1v, acc[1], 0, 0, 0);
  }

  // v = acc + bf2 + s1 ; row stats over full 256 cols
  float vv[2][4];
  float ps = 0.f, pq = 0.f;
#pragma unroll
  for (int n = 0; n < 2; ++n) {
    int col = w * 32 + n * 16 + fr;
    float bv = bf2[col];
#pragma unroll
    for (int r = 0; r < 4; ++r) {
      int rowl = kq * 4 + r;
      float v = acc[n][r] + bv + s1_lds[rowl][col];
      vv[n][r] = v;
    }
  }
#pragma unroll
  for (int r = 0; r < 4; ++r) {
    float sp = vv[0][r] + vv[1][r];
    float qp = vv[0][r] * vv[0][r] + vv[1][r] * vv[1][r];
    // butterfly over the 16 fr lanes (stays within kq group)
#pragma unroll
    for (int off = 1; off < 16; off <<= 1) {
      sp += __shfl_xor(sp, off);
      qp += __shfl_xor(qp, off);
    }
    if (fr == 0) {
      part_s[w][kq * 4 + r] = sp;
      part_q[w][kq * 4 + r] = qp;
    }
  }
  __syncthreads();
  if (tid < 16) {
    float S = 0.f, Q = 0.f;
#pragma unroll
    for (int ww = 0; ww < 8; ++ww) { S += part_s[ww][tid]; Q += part_q[ww][tid]; }
    float mu = S * (1.f / 256.f);
    float var = Q * (1.f / 256.f) - mu * mu;
    ln_mu[tid] = mu;
    ln_rs[tid] = rsqrtf(var + 1e-5f);
  }
  __syncthreads();
#pragma unroll
  for (int n = 0; n < 2; ++n) {
    int col = w * 32 + n * 16 + fr;
    float gv = g2[col], bv2 = b2[col];
#pragma unroll
    for (int r = 0; r < 4; ++r) {
      int rowl = kq * 4 + r;
      float y = (vv[n][r] - ln_mu[rowl]) * ln_rs[rowl] * gv + bv2;
      outf[(size_t)(m0 + rowl) * 256 + col] = y;
    }
  }
}

// --------------------------------------------------------------- MFMA attention
__global__ __launch_bounds__(512, 4) void attn_mfma(
    const unsigned short* __restrict__ qk, const unsigned short* __restrict__ vtg,
    const float* __restrict__ Wb,
    float* __restrict__ a_out, unsigned short* __restrict__ cat)
{
  __shared__ __align__(16) char P_lds[128 * 512];
  __shared__ float wb_lds[65];
  __shared__ float r_lds[128];
  __shared__ float ps_part[2][128], pr_part[2][128], sf_part[2][128];

  const int tid = threadIdx.x;
  const int w = tid >> 6, lane = tid & 63;
  const int iq = w & 3, jh = w >> 2;
  const int bh = blockIdx.y, b = bh >> 3, h = bh & 7;
  const int i0 = blockIdx.x * 128;
  const int l31 = lane & 31, hi = lane >> 5;

  if (tid < 65) wb_lds[tid] = Wb[tid * NH + h];

  if ((bh & 7) == 0) {
    for (int t = tid; t < 128 * 24; t += 512) {
      int r = t / 24, c = t - r * 24;
      cat[((size_t)b * N_TOK + i0 + r) * 1056 + 1032 + c] = 0;
    }
  }

  const int i_loc_l = iq * 32 + l31;
  const int i_glob_l = i0 + i_loc_l;
  const int pswz = i_loc_l & 31;

  const size_t qrow = ((size_t)b * N_TOK + i_glob_l) * 1024 + h * 64;
  bf16x8 qf[4];
#pragma unroll
  for (int ks = 0; ks < 4; ++ks)
    qf[ks] = *(const bf16x8*)(qk + qrow + ks * 16 + hi * 8);

  float psum = 0.f, pre = 0.f, suf = 0.f;
#pragma unroll
  for (int t4 = 0; t4 < 4; ++t4) {
    const int jrow = jh * 128 + t4 * 32 + l31;
    const size_t krow = ((size_t)b * N_TOK + jrow) * 1024 + 512 + h * 64;
    bf16x8 kf[4];
#pragma unroll
    for (int ks = 0; ks < 4; ++ks)
      kf[ks] = *(const bf16x8*)(qk + krow + ks * 16 + hi * 8);
    f32x16 st;
#pragma unroll
    for (int e = 0; e < 16; ++e) st[e] = 0.f;
    __builtin_amdgcn_s_setprio(1);
#pragma unroll
    for (int ks = 0; ks < 4; ++ks)
      st = __builtin_amdgcn_mfma_f32_32x32x16_bf16(kf[ks], qf[ks], st, 0, 0, 0);
    __builtin_amdgcn_s_setprio(0);
#pragma unroll
    for (int q = 0; q < 4; ++q) {
      union { unsigned short u4[4]; uint2 v; } pu;
#pragma unroll
      for (int r = 0; r < 4; ++r) {
        int j = jh * 128 + t4 * 32 + q * 8 + hi * 4 + r;
        int idx = j - i_glob_l + 32;
        idx = idx < 0 ? 0 : (idx > 64 ? 64 : idx);
        float lg = 0.70710678118654752f * (st[q * 4 + r] * 0.125f + wb_lds[idx]);
        float p = __expf(lg);
        psum += p;
        if (j <= i_glob_l - 32) pre += p;
        if (j >= i_glob_l + 32) suf += p;
        pu.u4[r] = f2bf(p);
      }
      int chunk = jh * 16 + t4 * 4 + q;
      *(uint2*)(P_lds + i_loc_l * 512 + ((chunk ^ pswz) << 4) + hi * 8) = pu.v;
    }
  }
  psum += __shfl_xor(psum, 32);
  pre  += __shfl_xor(pre, 32);
  suf  += __shfl_xor(suf, 32);
  if (hi == 0) {
    ps_part[jh][i_loc_l] = psum;
    pr_part[jh][i_loc_l] = pre;
    sf_part[jh][i_loc_l] = suf;
  }
  __syncthreads();
  if (tid < 128) r_lds[tid] = 1.f / (ps_part[0][tid] + ps_part[1][tid]);
  __syncthreads();

  f32x16 oacc;
#pragma unroll
  for (int e = 0; e < 16; ++e) oacc[e] = 0.f;
  const int crow = jh * 32 + l31;
  const unsigned short* vrow = vtg + ((size_t)bh * CH + crow) * N_TOK;
  __builtin_amdgcn_s_setprio(1);
#pragma unroll
  for (int ks = 0; ks < 16; ++ks) {
    bf16x8 pf = *(const bf16x8*)(P_lds + i_loc_l * 512 + (((2 * ks + hi) ^ pswz) << 4));
    bf16x8 vf = *(const bf16x8*)(vrow + ks * 16 + hi * 8);
    oacc = __builtin_amdgcn_mfma_f32_32x32x16_bf16(pf, vf, oacc, 0, 0, 0);
  }
  __builtin_amdgcn_s_setprio(0);
#pragma unroll
  for (int reg = 0; reg < 16; ++reg) {
    int rowp = (reg & 3) + 8 * (reg >> 2) + 4 * hi;
    int i_loc = iq * 32 + rowp;
    float rv = r_lds[i_loc];
    cat[((size_t)b * N_TOK + i0 + i_loc) * 1056 + 520 + h * CH + jh * 32 + l31] =
        f2bf(oacc[reg] * rv);
  }

  for (int rl = 0; rl < 16; ++rl) {
    int i_loc = w * 16 + rl;
    int ig = i0 + i_loc;
    float rv = r_lds[i_loc];
    int j0 = lane * 4;
    ushort4 pv = *(const ushort4*)(P_lds + i_loc * 512 +
        (((lane >> 1) ^ (i_loc & 31)) << 4) + (lane & 1) * 8);
    float4 av;
    av.x = bf2f(pv.x) * rv; av.y = bf2f(pv.y) * rv;
    av.z = bf2f(pv.z) * rv; av.w = bf2f(pv.w) * rv;
    *(float4*)(a_out + ((size_t)bh * N_TOK + ig) * N_TOK + j0) = av;

    unsigned short* crw = cat + ((size_t)b * N_TOK + ig) * 1056 + h * NB;
    const float* ap = (const float*)&av;
#pragma unroll
    for (int e = 0; e < 4; ++e) {
      int n = j0 + e - ig + 32;
      if (n >= 1 && n <= 63) crw[n] = f2bf(ap[e]);
    }
    if (lane == 0) {
      crw[0]  = f2bf((pr_part[0][i_loc] + pr_part[1][i_loc]) * rv);
      crw[64] = f2bf((sf_part[0][i_loc] + sf_part[1][i_loc]) * rv);
    }
  }
}

// ------------------------------------------------------------------- launch
extern "C" void kernel_launch(void* const* d_in, const int* in_sizes, int n_in,
                              void* d_out, int out_size, void* d_ws, size_t ws_size,
                              hipStream_t stream)
{
  const float* s   = (const float*)d_in[0];
  const float* Wq  = (const float*)d_in[2];
  const float* Wk  = (const float*)d_in[3];
  const float* Wv  = (const float*)d_in[4];
  const float* Wb  = (const float*)d_in[5];
  const float* Wo  = (const float*)d_in[6];
  const float* bo  = (const float*)d_in[7];
  const float* g1  = (const float*)d_in[8];
  const float* b1  = (const float*)d_in[9];
  const float* W1  = (const float*)d_in[10];
  const float* bf1 = (const float*)d_in[11];
  const float* W2  = (const float*)d_in[12];
  const float* bf2 = (const float*)d_in[13];
  const float* g2  = (const float*)d_in[14];
  const float* b2  = (const float*)d_in[15];

  float* out_s2 = (float*)d_out;
  float* a_out  = (float*)d_out + (size_t)16 * 256 * 256;

  char* wsb = (char*)d_ws;
  unsigned short* s_bf   = (unsigned short*)(wsb + 0);            // 2 MB
  unsigned short* wqkv_t = (unsigned short*)(wsb + 2097152);      // 768 KB
  unsigned short* wo_t   = (unsigned short*)(wsb + 2883584);      // 528 KB
  unsigned short* w1_t   = (unsigned short*)(wsb + 3424256);      // 512 KB
  unsigned short* w2_t   = (unsigned short*)(wsb + 3948544);      // 512 KB
  unsigned short* qk_bf  = (unsigned short*)(wsb + 4718592);      // 8 MB
  unsigned short* vt_bf  = (unsigned short*)(wsb + 13107200);     // 4 MB
  unsigned short* cat_bf = (unsigned short*)(wsb + 17301504);     // 8.65 MB
  float* s_upd = (float*)(wsb + 25952256);                        // 4 MB
  float* s1    = (float*)(wsb + 30146560);                        // 4 MB
  unsigned short* hbuf  = (unsigned short*)(wsb + 36438016);      // 8 MB

  dim3 thr(256);

  prep_all<<<1316, thr, 0, stream>>>(s, Wq, Wk, Wv, Wo, W1, W2,
                                     s_bf, wqkv_t, wo_t, w1_t, w2_t);

  gemm_mfma<<<dim3(12, 32), thr, 0, stream>>>(s_bf, wqkv_t, 4096, 1536, 256,
      qk_bf, vt_bf);

  attn_mfma<<<dim3(2, 128), dim3(512), 0, stream>>>(qk_bf, vt_bf, Wb, a_out, cat_bf);

  gemm_mfma64<<<dim3(4, 64), thr, 0, stream>>>(cat_bf, wo_t, 4096, 256, 1056,
      bo, s_upd, 256, s);

  gemm_ffn1<<<dim3(16, 64), thr, 0, stream>>>(s_upd, w1_t, g1, b1, bf1, hbuf, s1);

  gemm_ffn2<<<256, dim3(512), 0, stream>>>(hbuf, w2_t, bf2, s1, g2, b2, out_s2);
}

// Round 11
// 83.400 us; speedup vs baseline: 1.3349x; 1.3349x over previous
//
#include <hip/hip_runtime.h>
#include <hip/hip_bf16.h>

// PeptideSelfAttention: B=16 N=256 CS=256 CH=64 H=8 K=32 CT=1024 NB=65
// R11: R9 structure + split-K x2 on Wo (K=1056) and FFN2 (K=1024): grid
// (4,64,2), raw f32 partials into dead ws regions; LN kernels combine
// (pA+pB+bias+resid). Attention/QKV/prep identical to R9.

#define N_TOK 256
#define CH 64
#define NH 8
#define NB 65

typedef __attribute__((ext_vector_type(8))) __bf16 bf16x8;
typedef __attribute__((ext_vector_type(4))) float f32x4;
typedef __attribute__((ext_vector_type(16))) float f32x16;

__device__ inline unsigned short f2bf(float f) {
  unsigned int u = __float_as_uint(f);
  u = (u + 0x7FFFu + ((u >> 16) & 1u)) >> 16;
  return (unsigned short)u;
}
__device__ inline float bf2f(unsigned short u) {
  return __uint_as_float(((unsigned int)u) << 16);
}

// ------------------------------------------------------------ fused prep
__global__ __launch_bounds__(256) void prep_all(
    const float* __restrict__ s, const float* __restrict__ Wq,
    const float* __restrict__ Wk, const float* __restrict__ Wv,
    const float* __restrict__ Wo, const float* __restrict__ W1,
    const float* __restrict__ W2,
    unsigned short* __restrict__ s_bf, unsigned short* __restrict__ wqkv_t,
    unsigned short* __restrict__ wo_t, unsigned short* __restrict__ w1_t,
    unsigned short* __restrict__ w2_t)
{
  const int bid = blockIdx.x, tid = threadIdx.x;
  if (bid < 1024) {
    int idx = (bid * 256 + tid) * 4;
    float4 v = *(const float4*)(s + idx);
    ushort4 o;
    o.x = f2bf(v.x); o.y = f2bf(v.y); o.z = f2bf(v.z); o.w = f2bf(v.w);
    *(ushort4*)(s_bf + idx) = o;
    return;
  }
  int j = bid - 1024;
  const float* in; unsigned short* out;
  int R, C, ldout, r0, c0, qkvperm = 0;
  if (j < 96) {
    int mat = j / 32, jj = j % 32;
    r0 = (jj / 8) * 64; c0 = (jj % 8) * 64;
    in = (mat == 0) ? Wq : (mat == 1) ? Wk : Wv;
    R = 256; C = 512; out = wqkv_t + mat * 131072; ldout = 256; qkvperm = 1;
  } else if (j < 164) {
    int jj = j - 96;
    r0 = (jj / 4) * 64; c0 = (jj % 4) * 64;
    in = Wo; R = 1032; C = 256; out = wo_t; ldout = 1056;
  } else if (j < 228) {
    int jj = j - 164;
    r0 = (jj / 16) * 64; c0 = (jj % 16) * 64;
    in = W1; R = 256; C = 1024; out = w1_t; ldout = 256;
  } else {
    int jj = j - 228;
    r0 = (jj / 4) * 64; c0 = (jj % 4) * 64;
    in = W2; R = 1024; C = 256; out = w2_t; ldout = 1024;
  }
  __shared__ unsigned short lt[64][72];
#pragma unroll
  for (int it = 0; it < 4; ++it) {
    int kk = it * 16 + (tid >> 4);
    int cc = (tid & 15) * 4;
    float4 v = {0.f, 0.f, 0.f, 0.f};
    if (r0 + kk < R) v = *(const float4*)(in + (size_t)(r0 + kk) * C + c0 + cc);
    lt[cc + 0][kk] = f2bf(v.x); lt[cc + 1][kk] = f2bf(v.y);
    lt[cc + 2][kk] = f2bf(v.z); lt[cc + 3][kk] = f2bf(v.w);
  }
  __syncthreads();
  {
    int or_ = tid >> 2, chunk = tid & 3;
    int ocol0 = r0 + chunk * 16;
    int orow = c0 + or_;
    if (qkvperm) orow = (orow & 7) * 64 + (orow >> 3);
    if (ocol0 < ldout) {
      uint4 w0 = *(uint4*)&lt[or_][chunk * 16];
      uint4 w1 = *(uint4*)&lt[or_][chunk * 16 + 8];
      *(uint4*)(out + (size_t)orow * ldout + ocol0) = w0;
      *(uint4*)(out + (size_t)orow * ldout + ocol0 + 8) = w1;
    }
  }
}

// --------------------------------------------- 128x128 MFMA GEMM (QKV)
__global__ __launch_bounds__(256) void gemm_mfma(
    const unsigned short* __restrict__ A, const unsigned short* __restrict__ Bt,
    int M, int N, int K,
    unsigned short* __restrict__ qk, unsigned short* __restrict__ vt)
{
  __shared__ __align__(16) char Asb[4][8192];
  __shared__ __align__(16) char Bsb[4][8192];
  const int tid = threadIdx.x;
  const int w = tid >> 6, lane = tid & 63;
  const int wm = w >> 1, wn = w & 1;
  const int nbx = gridDim.x;
  int flat = blockIdx.y * nbx + blockIdx.x;
  int cpx = (nbx * gridDim.y) >> 3;
  int swz = (flat & 7) * cpx + (flat >> 3);
  const int m0 = (swz / nbx) * 128, n0 = (swz % nbx) * 128;
  const int fr = lane & 15, kq = lane >> 4;

  const unsigned short *pa[2], *pb[2];
  int ldsoff[2];
#pragma unroll
  for (int s2 = 0; s2 < 2; ++s2) {
    int inst = w * 2 + s2;
    int row = inst * 16 + (lane >> 2);
    int ch = (lane & 3) ^ ((row >> 1) & 3);
    pa[s2] = A + (size_t)(m0 + row) * K + ch * 8;
    pb[s2] = Bt + (size_t)(n0 + row) * K + ch * 8;
    ldsoff[s2] = inst * 1024;
  }
  auto stage = [&](int buf, int koff) {
#pragma unroll
    for (int s2 = 0; s2 < 2; ++s2) {
      __builtin_amdgcn_global_load_lds(
          (const __attribute__((address_space(1))) void*)(pa[s2] + koff),
          (__attribute__((address_space(3))) void*)(Asb[buf] + ldsoff[s2]), 16, 0, 0);
      __builtin_amdgcn_global_load_lds(
          (const __attribute__((address_space(1))) void*)(pb[s2] + koff),
          (__attribute__((address_space(3))) void*)(Bsb[buf] + ldsoff[s2]), 16, 0, 0);
    }
  };

  f32x4 acc[4][4];
#pragma unroll
  for (int m = 0; m < 4; ++m)
#pragma unroll
    for (int n = 0; n < 4; ++n)
#pragma unroll
      for (int e = 0; e < 4; ++e) acc[m][n][e] = 0.f;

  const int nsteps = K >> 5;
  stage(0, 0);
  if (nsteps > 1) stage(1, 32);
  if (nsteps > 2) stage(2, 64);

  for (int t = 0; t < nsteps; ++t) {
    if (t + 3 < nsteps) stage((t + 3) & 3, (t + 3) * 32);
    int ahead = nsteps - 1 - t; if (ahead > 3) ahead = 3;
    switch (ahead) {
      case 3: asm volatile("s_waitcnt vmcnt(12)" ::: "memory"); break;
      case 2: asm volatile("s_waitcnt vmcnt(8)" ::: "memory"); break;
      case 1: asm volatile("s_waitcnt vmcnt(4)" ::: "memory"); break;
      default: asm volatile("s_waitcnt vmcnt(0)" ::: "memory"); break;
    }
    __builtin_amdgcn_s_barrier();

    const char* Ac = Asb[t & 3];
    const char* Bc = Bsb[t & 3];
    bf16x8 af[4], bfr[4];
#pragma unroll
    for (int m = 0; m < 4; ++m) {
      int r = wm * 64 + m * 16 + fr;
      af[m] = *(const bf16x8*)(Ac + r * 64 + ((kq ^ ((r >> 1) & 3)) << 4));
    }
#pragma unroll
    for (int n = 0; n < 4; ++n) {
      int r = wn * 64 + n * 16 + fr;
      bfr[n] = *(const bf16x8*)(Bc + r * 64 + ((kq ^ ((r >> 1) & 3)) << 4));
    }
#pragma unroll
    for (int m = 0; m < 4; ++m)
#pragma unroll
      for (int n = 0; n < 4; ++n)
        acc[m][n] = __builtin_amdgcn_mfma_f32_16x16x32_bf16(af[m], bfr[n], acc[m][n], 0, 0, 0);

    __builtin_amdgcn_s_barrier();
  }

  const int colbase = n0 + wn * 64;
  const int rowbase = m0 + wm * 64 + kq * 4;
#pragma unroll
  for (int mi = 0; mi < 4; ++mi)
#pragma unroll
    for (int ni = 0; ni < 4; ++ni) {
      int col = colbase + ni * 16 + fr;
      int rb = rowbase + mi * 16;
      if (col < 1024) {
#pragma unroll
        for (int r = 0; r < 4; ++r)
          qk[(size_t)(rb + r) * 1024 + col] = f2bf(acc[mi][ni][r]);
      } else {
        int r2 = col & 511;
        int h = r2 >> 6, c = r2 & 63;
        int b = rb >> 8, i = rb & 255;
        union { unsigned short u4[4]; uint2 v; } pk;
#pragma unroll
        for (int r = 0; r < 4; ++r) pk.u4[r] = f2bf(acc[mi][ni][r]);
        *(uint2*)(vt + (((size_t)(b * NH + h)) * CH + c) * N_TOK + i) = pk.v;
      }
    }
}

// ------------------------------- 64x64 MFMA GEMM, split-K (raw f32 partials)
// grid (nx, ny, 2): z selects K window and output buffer.
__global__ __launch_bounds__(256) void gemm_split(
    const unsigned short* __restrict__ A, const unsigned short* __restrict__ Bt,
    int ldk, int koff0, int klen0, int koff1, int klen1,
    float* __restrict__ CfA, float* __restrict__ CfB, int ldc)
{
  __shared__ __align__(16) char Asb[4][4096];
  __shared__ __align__(16) char Bsb[4][4096];
  const int tid = threadIdx.x;
  const int w = tid >> 6, lane = tid & 63;
  const int wm = w >> 1, wn = w & 1;
  const int m0 = blockIdx.y * 64, n0 = blockIdx.x * 64;
  const int fr = lane & 15, kq = lane >> 4;
  const int z = blockIdx.z;
  const int koff = z ? koff1 : koff0;
  const int klen = z ? klen1 : klen0;
  float* Cf = z ? CfB : CfA;

  const int srow = w * 16 + (lane >> 2);
  const int sch = (lane & 3) ^ ((srow >> 1) & 3);
  const unsigned short* pa = A + (size_t)(m0 + srow) * ldk + koff + sch * 8;
  const unsigned short* pb = Bt + (size_t)(n0 + srow) * ldk + koff + sch * 8;

  auto stage = [&](int buf, int ko) {
    __builtin_amdgcn_global_load_lds(
        (const __attribute__((address_space(1))) void*)(pa + ko),
        (__attribute__((address_space(3))) void*)(Asb[buf] + w * 1024), 16, 0, 0);
    __builtin_amdgcn_global_load_lds(
        (const __attribute__((address_space(1))) void*)(pb + ko),
        (__attribute__((address_space(3))) void*)(Bsb[buf] + w * 1024), 16, 0, 0);
  };

  f32x4 acc[2][2];
#pragma unroll
  for (int m = 0; m < 2; ++m)
#pragma unroll
    for (int n = 0; n < 2; ++n)
#pragma unroll
      for (int e = 0; e < 4; ++e) acc[m][n][e] = 0.f;

  const int nsteps = klen >> 5;
  stage(0, 0);
  if (nsteps > 1) stage(1, 32);
  if (nsteps > 2) stage(2, 64);

  for (int t = 0; t < nsteps; ++t) {
    if (t + 3 < nsteps) stage((t + 3) & 3, (t + 3) * 32);
    int ahead = nsteps - 1 - t; if (ahead > 3) ahead = 3;
    switch (ahead) {
      case 3: asm volatile("s_waitcnt vmcnt(6)" ::: "memory"); break;
      case 2: asm volatile("s_waitcnt vmcnt(4)" ::: "memory"); break;
      case 1: asm volatile("s_waitcnt vmcnt(2)" ::: "memory"); break;
      default: asm volatile("s_waitcnt vmcnt(0)" ::: "memory"); break;
    }
    __builtin_amdgcn_s_barrier();

    const char* Ac = Asb[t & 3];
    const char* Bc = Bsb[t & 3];
    bf16x8 af[2], bfr[2];
#pragma unroll
    for (int m = 0; m < 2; ++m) {
      int r = wm * 32 + m * 16 + fr;
      af[m] = *(const bf16x8*)(Ac + r * 64 + ((kq ^ ((r >> 1) & 3)) << 4));
    }
#pragma unroll
    for (int n = 0; n < 2; ++n) {
      int r = wn * 32 + n * 16 + fr;
      bfr[n] = *(const bf16x8*)(Bc + r * 64 + ((kq ^ ((r >> 1) & 3)) << 4));
    }
#pragma unroll
    for (int m = 0; m < 2; ++m)
#pragma unroll
      for (int n = 0; n < 2; ++n)
        acc[m][n] = __builtin_amdgcn_mfma_f32_16x16x32_bf16(af[m], bfr[n], acc[m][n], 0, 0, 0);

    __builtin_amdgcn_s_barrier();
  }

  const int colbase = n0 + wn * 32;
  const int rowbase = m0 + wm * 32 + kq * 4;
#pragma unroll
  for (int mi = 0; mi < 2; ++mi)
#pragma unroll
    for (int ni = 0; ni < 2; ++ni) {
      int col = colbase + ni * 16 + fr;
      int rb = rowbase + mi * 16;
#pragma unroll
      for (int r = 0; r < 4; ++r)
        Cf[(size_t)(rb + r) * ldc + col] = acc[mi][ni][r];
    }
}

// --------------------------------------------- 64x64 MFMA GEMM (FFN1, relu)
__global__ __launch_bounds__(256) void gemm_relu(
    const unsigned short* __restrict__ A, const unsigned short* __restrict__ Bt,
    int N, int K, const float* __restrict__ bias, unsigned short* __restrict__ Cb)
{
  __shared__ __align__(16) char Asb[4][4096];
  __shared__ __align__(16) char Bsb[4][4096];
  const int tid = threadIdx.x;
  const int w = tid >> 6, lane = tid & 63;
  const int wm = w >> 1, wn = w & 1;
  const int m0 = blockIdx.y * 64, n0 = blockIdx.x * 64;
  const int fr = lane & 15, kq = lane >> 4;

  const int srow = w * 16 + (lane >> 2);
  const int sch = (lane & 3) ^ ((srow >> 1) & 3);
  const unsigned short* pa = A + (size_t)(m0 + srow) * K + sch * 8;
  const unsigned short* pb = Bt + (size_t)(n0 + srow) * K + sch * 8;

  auto stage = [&](int buf, int koff) {
    __builtin_amdgcn_global_load_lds(
        (const __attribute__((address_space(1))) void*)(pa + koff),
        (__attribute__((address_space(3))) void*)(Asb[buf] + w * 1024), 16, 0, 0);
    __builtin_amdgcn_global_load_lds(
        (const __attribute__((address_space(1))) void*)(pb + koff),
        (__attribute__((address_space(3))) void*)(Bsb[buf] + w * 1024), 16, 0, 0);
  };

  f32x4 acc[2][2];
#pragma unroll
  for (int m = 0; m < 2; ++m)
#pragma unroll
    for (int n = 0; n < 2; ++n)
#pragma unroll
      for (int e = 0; e < 4; ++e) acc[m][n][e] = 0.f;

  const int nsteps = K >> 5;
  stage(0, 0);
  if (nsteps > 1) stage(1, 32);
  if (nsteps > 2) stage(2, 64);

  for (int t = 0; t < nsteps; ++t) {
    if (t + 3 < nsteps) stage((t + 3) & 3, (t + 3) * 32);
    int ahead = nsteps - 1 - t; if (ahead > 3) ahead = 3;
    switch (ahead) {
      case 3: asm volatile("s_waitcnt vmcnt(6)" ::: "memory"); break;
      case 2: asm volatile("s_waitcnt vmcnt(4)" ::: "memory"); break;
      case 1: asm volatile("s_waitcnt vmcnt(2)" ::: "memory"); break;
      default: asm volatile("s_waitcnt vmcnt(0)" ::: "memory"); break;
    }
    __builtin_amdgcn_s_barrier();

    const char* Ac = Asb[t & 3];
    const char* Bc = Bsb[t & 3];
    bf16x8 af[2], bfr[2];
#pragma unroll
    for (int m = 0; m < 2; ++m) {
      int r = wm * 32 + m * 16 + fr;
      af[m] = *(const bf16x8*)(Ac + r * 64 + ((kq ^ ((r >> 1) & 3)) << 4));
    }
#pragma unroll
    for (int n = 0; n < 2; ++n) {
      int r = wn * 32 + n * 16 + fr;
      bfr[n] = *(const bf16x8*)(Bc + r * 64 + ((kq ^ ((r >> 1) & 3)) << 4));
    }
#pragma unroll
    for (int m = 0; m < 2; ++m)
#pragma unroll
      for (int n = 0; n < 2; ++n)
        acc[m][n] = __builtin_amdgcn_mfma_f32_16x16x32_bf16(af[m], bfr[n], acc[m][n], 0, 0, 0);

    __builtin_amdgcn_s_barrier();
  }

  const int colbase = n0 + wn * 32;
  const int rowbase = m0 + wm * 32 + kq * 4;
#pragma unroll
  for (int mi = 0; mi < 2; ++mi)
#pragma unroll
    for (int ni = 0; ni < 2; ++ni) {
      int col = colbase + ni * 16 + fr;
      int rb = rowbase + mi * 16;
      float bv = bias[col];
#pragma unroll
      for (int r = 0; r < 4; ++r)
        Cb[(size_t)(rb + r) * N + col] = f2bf(fmaxf(acc[mi][ni][r] + bv, 0.f));
    }
}

// --------------------------------------------------------------- MFMA attention
__global__ __launch_bounds__(512, 4) void attn_mfma(
    const unsigned short* __restrict__ qk, const unsigned short* __restrict__ vtg,
    const float* __restrict__ Wb,
    float* __restrict__ a_out, unsigned short* __restrict__ cat)
{
  __shared__ __align__(16) char P_lds[128 * 512];
  __shared__ float wb_lds[65];
  __shared__ float r_lds[128];
  __shared__ float ps_part[2][128], pr_part[2][128], sf_part[2][128];

  const int tid = threadIdx.x;
  const int w = tid >> 6, lane = tid & 63;
  const int iq = w & 3, jh = w >> 2;
  const int bh = blockIdx.y, b = bh >> 3, h = bh & 7;
  const int i0 = blockIdx.x * 128;
  const int l31 = lane & 31, hi = lane >> 5;

  if (tid < 65) wb_lds[tid] = Wb[tid * NH + h];

  if ((bh & 7) == 0) {
    for (int t = tid; t < 128 * 24; t += 512) {
      int r = t / 24, c = t - r * 24;
      cat[((size_t)b * N_TOK + i0 + r) * 1056 + 1032 + c] = 0;
    }
  }

  const int i_loc_l = iq * 32 + l31;
  const int i_glob_l = i0 + i_loc_l;
  const int pswz = i_loc_l & 31;

  const size_t qrow = ((size_t)b * N_TOK + i_glob_l) * 1024 + h * 64;
  bf16x8 qf[4];
#pragma unroll
  for (int ks = 0; ks < 4; ++ks)
    qf[ks] = *(const bf16x8*)(qk + qrow + ks * 16 + hi * 8);

  float psum = 0.f, pre = 0.f, suf = 0.f;
#pragma unroll
  for (int t4 = 0; t4 < 4; ++t4) {
    const int jrow = jh * 128 + t4 * 32 + l31;
    const size_t krow = ((size_t)b * N_TOK + jrow) * 1024 + 512 + h * 64;
    bf16x8 kf[4];
#pragma unroll
    for (int ks = 0; ks < 4; ++ks)
      kf[ks] = *(const bf16x8*)(qk + krow + ks * 16 + hi * 8);
    f32x16 st;
#pragma unroll
    for (int e = 0; e < 16; ++e) st[e] = 0.f;
    __builtin_amdgcn_s_setprio(1);
#pragma unroll
    for (int ks = 0; ks < 4; ++ks)
      st = __builtin_amdgcn_mfma_f32_32x32x16_bf16(kf[ks], qf[ks], st, 0, 0, 0);
    __builtin_amdgcn_s_setprio(0);
#pragma unroll
    for (int q = 0; q < 4; ++q) {
      union { unsigned short u4[4]; uint2 v; } pu;
#pragma unroll
      for (int r = 0; r < 4; ++r) {
        int j = jh * 128 + t4 * 32 + q * 8 + hi * 4 + r;
        int idx = j - i_glob_l + 32;
        idx = idx < 0 ? 0 : (idx > 64 ? 64 : idx);
        float lg = 0.70710678118654752f * (st[q * 4 + r] * 0.125f + wb_lds[idx]);
        float p = __expf(lg);
        psum += p;
        if (j <= i_glob_l - 32) pre += p;
        if (j >= i_glob_l + 32) suf += p;
        pu.u4[r] = f2bf(p);
      }
      int chunk = jh * 16 + t4 * 4 + q;
      *(uint2*)(P_lds + i_loc_l * 512 + ((chunk ^ pswz) << 4) + hi * 8) = pu.v;
    }
  }
  psum += __shfl_xor(psum, 32);
  pre  += __shfl_xor(pre, 32);
  suf  += __shfl_xor(suf, 32);
  if (hi == 0) {
    ps_part[jh][i_loc_l] = psum;
    pr_part[jh][i_loc_l] = pre;
    sf_part[jh][i_loc_l] = suf;
  }
  __syncthreads();
  if (tid < 128) r_lds[tid] = 1.f / (ps_part[0][tid] + ps_part[1][tid]);
  __syncthreads();

  f32x16 oacc;
#pragma unroll
  for (int e = 0; e < 16; ++e) oacc[e] = 0.f;
  const int crow = jh * 32 + l31;
  const unsigned short* vrow = vtg + ((size_t)bh * CH + crow) * N_TOK;
  __builtin_amdgcn_s_setprio(1);
#pragma unroll
  for (int ks = 0; ks < 16; ++ks) {
    bf16x8 pf = *(const bf16x8*)(P_lds + i_loc_l * 512 + (((2 * ks + hi) ^ pswz) << 4));
    bf16x8 vf = *(const bf16x8*)(vrow + ks * 16 + hi * 8);
    oacc = __builtin_amdgcn_mfma_f32_32x32x16_bf16(pf, vf, oacc, 0, 0, 0);
  }
  __builtin_amdgcn_s_setprio(0);
#pragma unroll
  for (int reg = 0; reg < 16; ++reg) {
    int rowp = (reg & 3) + 8 * (reg >> 2) + 4 * hi;
    int i_loc = iq * 32 + rowp;
    float rv = r_lds[i_loc];
    cat[((size_t)b * N_TOK + i0 + i_loc) * 1056 + 520 + h * CH + jh * 32 + l31] =
        f2bf(oacc[reg] * rv);
  }

  for (int rl = 0; rl < 16; ++rl) {
    int i_loc = w * 16 + rl;
    int ig = i0 + i_loc;
    float rv = r_lds[i_loc];
    int j0 = lane * 4;
    ushort4 pv = *(const ushort4*)(P_lds + i_loc * 512 +
        (((lane >> 1) ^ (i_loc & 31)) << 4) + (lane & 1) * 8);
    float4 av;
    av.x = bf2f(pv.x) * rv; av.y = bf2f(pv.y) * rv;
    av.z = bf2f(pv.z) * rv; av.w = bf2f(pv.w) * rv;
    *(float4*)(a_out + ((size_t)bh * N_TOK + ig) * N_TOK + j0) = av;

    unsigned short* crw = cat + ((size_t)b * N_TOK + ig) * 1056 + h * NB;
    const float* ap = (const float*)&av;
#pragma unroll
    for (int e = 0; e < 4; ++e) {
      int n = j0 + e - ig + 32;
      if (n >= 1 && n <= 63) crw[n] = f2bf(ap[e]);
    }
    if (lane == 0) {
      crw[0]  = f2bf((pr_part[0][i_loc] + pr_part[1][i_loc]) * rv);
      crw[64] = f2bf((sf_part[0][i_loc] + sf_part[1][i_loc]) * rv);
    }
  }
}

// ------------------------------------------ layernorm of (pA + pB + bias + resid)
__device__ inline float wave_sum(float v) {
#pragma unroll
  for (int off = 32; off; off >>= 1) v += __shfl_xor(v, off);
  return v;
}

__global__ __launch_bounds__(256) void ln_comb_kernel(
    const float* __restrict__ pA, const float* __restrict__ pB,
    const float* __restrict__ bias, const float* __restrict__ resid,
    const float* __restrict__ g, const float* __restrict__ bb,
    float* __restrict__ out, unsigned short* __restrict__ outbf)
{
  const int row = blockIdx.x, tid = threadIdx.x;
  const int wave = tid >> 6, lane = tid & 63;
  size_t idx = (size_t)row * 256 + tid;
  float x = pA[idx] + pB[idx] + bias[tid] + resid[idx];
  __shared__ float red[8];
  float s = wave_sum(x);
  if (lane == 0) red[wave] = s;
  __syncthreads();
  float mean = (red[0] + red[1] + red[2] + red[3]) * (1.f / 256.f);
  float d = x - mean;
  float s2 = wave_sum(d * d);
  if (lane == 0) red[4 + wave] = s2;
  __syncthreads();
  float var = (red[4] + red[5] + red[6] + red[7]) * (1.f / 256.f);
  float y = d * rsqrtf(var + 1e-5f) * g[tid] + bb[tid];
  out[idx] = y;
  if (outbf) outbf[idx] = f2bf(y);
}

// ------------------------------------------------------------------- launch
extern "C" void kernel_launch(void* const* d_in, const int* in_sizes, int n_in,
                              void* d_out, int out_size, void* d_ws, size_t ws_size,
                              hipStream_t stream)
{
  const float* s   = (const float*)d_in[0];
  const float* Wq  = (const float*)d_in[2];
  const float* Wk  = (const float*)d_in[3];
  const float* Wv  = (const float*)d_in[4];
  const float* Wb  = (const float*)d_in[5];
  const float* Wo  = (const float*)d_in[6];
  const float* bo  = (const float*)d_in[7];
  const float* g1  = (const float*)d_in[8];
  const float* b1  = (const float*)d_in[9];
  const float* W1  = (const float*)d_in[10];
  const float* bf1 = (const float*)d_in[11];
  const float* W2  = (const float*)d_in[12];
  const float* bf2 = (const float*)d_in[13];
  const float* g2  = (const float*)d_in[14];
  const float* b2  = (const float*)d_in[15];

  float* out_s2 = (float*)d_out;
  float* a_out  = (float*)d_out + (size_t)16 * 256 * 256;

  char* wsb = (char*)d_ws;
  unsigned short* s_bf   = (unsigned short*)(wsb + 0);            // 2 MB
  unsigned short* wqkv_t = (unsigned short*)(wsb + 2097152);      // 768 KB
  unsigned short* wo_t   = (unsigned short*)(wsb + 2883584);      // 528 KB
  unsigned short* w1_t   = (unsigned short*)(wsb + 3424256);      // 512 KB
  unsigned short* w2_t   = (unsigned short*)(wsb + 3948544);      // 512 KB
  unsigned short* qk_bf  = (unsigned short*)(wsb + 4718592);      // 8 MB [dead after attn]
  unsigned short* vt_bf  = (unsigned short*)(wsb + 13107200);     // 4 MB [dead after attn]
  unsigned short* cat_bf = (unsigned short*)(wsb + 17301504);     // 8.65 MB
  float* s_updA = (float*)(wsb + 25952256);                       // 4 MB
  float* s_updB = (float*)(wsb + 4718592);                        // reuse qk (1st half)
  float* ffA    = (float*)(wsb + 13107200);                       // reuse vt
  float* ffB    = (float*)(wsb + 8912896);                        // reuse qk (2nd half)
  float* s1     = (float*)(wsb + 30146560);                       // 4 MB
  unsigned short* s1_bf = (unsigned short*)(wsb + 34340864);      // 2 MB
  unsigned short* hbuf  = (unsigned short*)(wsb + 36438016);      // 8 MB

  dim3 thr(256);

  prep_all<<<1316, thr, 0, stream>>>(s, Wq, Wk, Wv, Wo, W1, W2,
                                     s_bf, wqkv_t, wo_t, w1_t, w2_t);

  gemm_mfma<<<dim3(12, 32), thr, 0, stream>>>(s_bf, wqkv_t, 4096, 1536, 256,
      qk_bf, vt_bf);

  attn_mfma<<<dim3(2, 128), dim3(512), 0, stream>>>(qk_bf, vt_bf, Wb, a_out, cat_bf);

  // Wo split-K: z0 = K[0,544), z1 = K[544,1056)
  gemm_split<<<dim3(4, 64, 2), thr, 0, stream>>>(cat_bf, wo_t, 1056,
      0, 544, 544, 512, s_updA, s_updB, 256);
  ln_comb_kernel<<<4096, thr, 0, stream>>>(s_updA, s_updB, bo, s, g1, b1, s1, s1_bf);

  gemm_relu<<<dim3(16, 64), thr, 0, stream>>>(s1_bf, w1_t, 1024, 256, bf1, hbuf);

  // FFN2 split-K: z0 = K[0,512), z1 = K[512,1024)
  gemm_split<<<dim3(4, 64, 2), thr, 0, stream>>>(hbuf, w2_t, 1024,
      0, 512, 512, 512, ffA, ffB, 256);
  ln_comb_kernel<<<4096, thr, 0, stream>>>(ffA, ffB, bf2, s1, g2, b2, out_s2, nullptr);
}